// Round 10
// baseline (806.131 us; speedup 1.0000x reference)
//
#include <hip/hip_runtime.h>

#define N_NODES 50000
#define N_EDGES 600000
#define N_GRAPHS 500
#define IN_F 92
#define HID 64
#define EDGE_F 41
#define ZDIM 169
#define PRED 128
#define BN_EPS 1e-5f
#define SCAN_BLOCKS 196          // ceil(50000/256)
#define ROW_U32 24               // eapS row = 48 f16 = 96 B
#define LOG2E 1.4426950408889634f
#define LN2   0.6931471805599453f
#define NAGG_BLOCKS 2048
#define NW2 (NAGG_BLOCKS * 8)    // 4 waves/block x 2 contexts
#define PART_T ((N_EDGES + 1 + NW2 - 1) / NW2)

typedef unsigned int u32;
typedef _Float16 f16;
typedef _Float16 f16x2 __attribute__((ext_vector_type(2)));
typedef _Float16 f16x8 __attribute__((ext_vector_type(8)));
typedef float f32x4 __attribute__((ext_vector_type(4)));

__device__ __forceinline__ u32 f2bf(float f) {
    u32 u = __float_as_uint(f);
    return (u + 0x7fffu + ((u >> 16) & 1u)) >> 16;
}

// first idx in [0, nelem) with a[idx] >= val (a sorted ascending)
__device__ __forceinline__ int lbound(const int* __restrict__ a, int nelem, int val) {
    int lo = 0, hi = nelem;
    while (lo < hi) {
        int m = (lo + hi) >> 1;
        if (a[m] < val) lo = m + 1; else hi = m;
    }
    return lo;
}

// ---------------- prep: all weight prep + zeroing + graph starts -------------
__global__ void k_prep(const float* __restrict__ Wsig, const float* __restrict__ Wsp,
                       const float* __restrict__ Wemb, const int* __restrict__ gidx,
                       f16* __restrict__ Wf16, f16* __restrict__ Wp2,
                       f16* __restrict__ Wef, int* __restrict__ gstart,
                       int* __restrict__ zeroBase) {
    int t = blockIdx.x * 256 + threadIdx.x;
    if (t < 3072) {
        int lane = t & 63;
        int jt = (t >> 6) & 7;
        int kt = (t >> 9) & 1;
        int L = t >> 10;
        int j128 = jt * 16 + (lane & 15);
        const float* Wbase = (j128 < 64) ? Wsig : Wsp;
        int j = j128 & 63;
        f16x8 v;
        #pragma unroll
        for (int b = 0; b < 8; ++b) {
            int k = kt * 32 + (lane >> 4) * 8 + b;
            float f = (k < EDGE_F) ? Wbase[(size_t)L * ZDIM * HID + (128 + k) * HID + j] * LOG2E : 0.f;
            v[b] = (f16)f;
        }
        *(f16x8*)(Wf16 + ((size_t)((L * 2 + kt) * 8 + jt) * 64 + lane) * 8) = v;
    } else if (t < 9216) {
        int t2 = t - 3072;
        int lane = t2 & 63;
        int jt = (t2 >> 6) & 15;
        int kt = (t2 >> 10) & 1;
        int L = t2 >> 11;
        int j256 = jt * 16 + (lane & 15);
        const float* Wbase = (j256 & 64) ? Wsp : Wsig;
        int rowoff = (j256 & 128) ? 64 : 0;
        int j = j256 & 63;
        f16x8 v;
        #pragma unroll
        for (int b = 0; b < 8; ++b) {
            int k = kt * 32 + (lane >> 4) * 8 + b;
            v[b] = (f16)Wbase[(size_t)L * ZDIM * HID + (rowoff + k) * HID + j];
        }
        *(f16x8*)(Wp2 + ((size_t)((L * 2 + kt) * 16 + jt) * 64 + lane) * 8) = v;
    } else if (t < 9984) {
        int t3 = t - 9216;
        int lane = t3 & 63;
        int jt = (t3 >> 6) & 3;
        int kt = t3 >> 8;    // 0..2
        int j = jt * 16 + (lane & 15);
        f16x8 v;
        #pragma unroll
        for (int b = 0; b < 8; ++b) {
            int k = kt * 32 + (lane >> 4) * 8 + b;
            v[b] = (k < IN_F) ? (f16)Wemb[(size_t)k * HID + j] : (f16)0.f;
        }
        *(f16x8*)(Wef + ((size_t)(kt * 4 + jt) * 64 + lane) * 8) = v;
    } else if (t < 10485) {
        int g = t - 9984;    // 0..500
        gstart[g] = lbound(gidx, N_NODES, g);
    } else if (t < 10485 + 2 * N_NODES) {
        zeroBase[t - 10485] = 0;
    }
}

__global__ void k_hist(const int* __restrict__ dst, int* __restrict__ deg) {
    int e = blockIdx.x * 256 + threadIdx.x;
    if (e < N_EDGES) atomicAdd(&deg[dst[e]], 1);
}

__global__ __launch_bounds__(256) void k_scanA(const int* __restrict__ deg,
                                               int* __restrict__ partial) {
    __shared__ int s[256];
    int i = blockIdx.x * 256 + threadIdx.x;
    s[threadIdx.x] = (i < N_NODES) ? deg[i] : 0;
    __syncthreads();
    for (int off = 128; off > 0; off >>= 1) {
        if (threadIdx.x < off) s[threadIdx.x] += s[threadIdx.x + off];
        __syncthreads();
    }
    if (threadIdx.x == 0) partial[blockIdx.x] = s[0];
}

__global__ __launch_bounds__(256) void k_scanB(const int* __restrict__ partial,
                                               int* __restrict__ partialExc,
                                               int* __restrict__ rowptr) {
    __shared__ int s[256];
    int t = threadIdx.x;
    int v = (t < SCAN_BLOCKS) ? partial[t] : 0;
    s[t] = v;
    __syncthreads();
    for (int off = 1; off < 256; off <<= 1) {
        int x = (t >= off) ? s[t - off] : 0;
        __syncthreads();
        s[t] += x;
        __syncthreads();
    }
    partialExc[t] = s[t] - v;
    if (t == 0) rowptr[N_NODES] = N_EDGES;
}

__global__ __launch_bounds__(256) void k_scanC(const int* __restrict__ deg,
                                               const int* __restrict__ partialExc,
                                               int* __restrict__ rowptr) {
    __shared__ int s[256];
    int i = blockIdx.x * 256 + threadIdx.x;
    int t = threadIdx.x;
    int v = (i < N_NODES) ? deg[i] : 0;
    s[t] = v;
    __syncthreads();
    for (int off = 1; off < 256; off <<= 1) {
        int x = (t >= off) ? s[t - off] : 0;
        __syncthreads();
        s[t] += x;
        __syncthreads();
    }
    if (i < N_NODES) rowptr[i] = s[t] - v + partialExc[blockIdx.x];
}

// ---------------- rank: CSR slot assignment + wave partition -----------------
__global__ void k_rank(const int* __restrict__ dst, const int* __restrict__ src,
                       const int* __restrict__ rowptr, int* __restrict__ cursor,
                       int* __restrict__ srcS, int* __restrict__ iperm,
                       int* __restrict__ partW) {
    int e = blockIdx.x * 256 + threadIdx.x;
    if (e <= NW2) partW[e] = min(lbound(rowptr, N_NODES + 1, e * PART_T), N_NODES);
    if (e >= N_EDGES) {
        if (e < N_EDGES + 32) srcS[e] = 0;   // pad: prefetch reads stay in-bounds
        return;
    }
    int d = dst[e];
    int p = rowptr[d] + atomicAdd(&cursor[d], 1);
    srcS[p] = src[e];
    iperm[p] = e;
}

// ---------------- epackS: gather-permute ea rows -> f16, 96 B rows ----------
__global__ __launch_bounds__(256) void k_epackS(const float* __restrict__ ea,
                                                const int* __restrict__ iperm,
                                                u32* __restrict__ eapS) {
    const int total = N_EDGES * ROW_U32;
    const int stride = gridDim.x * 256;
    for (int idx = blockIdx.x * 256 + threadIdx.x; idx < total; idx += stride) {
        int p = idx / ROW_U32;
        int q = idx - p * ROW_U32;
        int e = iperm[p];
        int k0 = 2 * q, k1 = k0 + 1;
        float f0 = (k0 < EDGE_F) ? ea[(size_t)e * EDGE_F + k0] : 0.f;
        float f1 = (k1 < EDGE_F) ? ea[(size_t)e * EDGE_F + k1] : 0.f;
        f16x2 hv = {(f16)f0, (f16)f1};
        eapS[idx] = __builtin_bit_cast(u32, hv);
    }
}

// ---------------- embedm: A = x @ W_embed + b via MFMA ----------------------
__global__ __launch_bounds__(256) void k_embedm(const float* __restrict__ x,
                                                const f16* __restrict__ Wef,
                                                const float* __restrict__ b,
                                                float* __restrict__ A) {
    __shared__ f16x8 Wl[12 * 64];   // 12 KB
    for (int i = threadIdx.x; i < 12 * 64; i += 256) Wl[i] = ((const f16x8*)Wef)[i];
    __syncthreads();
    const int lane = threadIdx.x & 63;
    const int col = lane & 15, grp = lane >> 4;
    float bj[4];
    #pragma unroll
    for (int jt = 0; jt < 4; ++jt) bj[jt] = b[jt * 16 + col];
    const int wid = blockIdx.x * 4 + (threadIdx.x >> 6);
    const int nw = gridDim.x * 4;
    for (int c = wid; c < N_NODES / 16; c += nw) {
        const int node = c * 16 + col;
        const float* xr = x + (size_t)node * IN_F;
        f16x8 af[3];
        #pragma unroll
        for (int kt = 0; kt < 3; ++kt) {
            int base = kt * 32 + grp * 8;
            float4 v0 = *(const float4*)(xr + base);
            float4 v1 = (base + 4 < IN_F) ? *(const float4*)(xr + base + 4)
                                          : make_float4(0.f, 0.f, 0.f, 0.f);
            af[kt] = f16x8{(f16)v0.x, (f16)v0.y, (f16)v0.z, (f16)v0.w,
                           (f16)v1.x, (f16)v1.y, (f16)v1.z, (f16)v1.w};
        }
        #pragma unroll
        for (int jt = 0; jt < 4; ++jt) {
            f32x4 c4 = {};
            c4 = __builtin_amdgcn_mfma_f32_16x16x32_f16(af[0], Wl[(0 * 4 + jt) * 64 + lane], c4, 0, 0, 0);
            c4 = __builtin_amdgcn_mfma_f32_16x16x32_f16(af[1], Wl[(1 * 4 + jt) * 64 + lane], c4, 0, 0, 0);
            c4 = __builtin_amdgcn_mfma_f32_16x16x32_f16(af[2], Wl[(2 * 4 + jt) * 64 + lane], c4, 0, 0, 0);
            #pragma unroll
            for (int r = 0; r < 4; ++r)
                A[(size_t)(c * 16 + grp * 4 + r) * HID + jt * 16 + col] = c4[r] + bj[jt];
        }
    }
}

// ---------------- projm: MFMA node projections (R8 layout: [n][jt*16+col]) ---
__global__ __launch_bounds__(256, 4) void k_projm(const float* __restrict__ A,
                                                  const float* __restrict__ statsPrev,
                                                  const float* __restrict__ gammaP,
                                                  const float* __restrict__ betaP,
                                                  int applyBN,
                                                  const f16* __restrict__ Wp2L,
                                                  const float* __restrict__ bsig,
                                                  const float* __restrict__ bsp,
                                                  u32* __restrict__ pA,
                                                  u32* __restrict__ pB,
                                                  float* __restrict__ statsOut) {
    __shared__ f16x8 Wl[32 * 64];   // 32 KB
    for (int i = threadIdx.x; i < 32 * 64; i += 256) Wl[i] = ((const f16x8*)Wp2L)[i];
    if (blockIdx.x == 0)
        for (int i = threadIdx.x; i < 128 * 32; i += 256) statsOut[i] = 0.f;
    __syncthreads();
    const int lane = threadIdx.x & 63;
    const int col = lane & 15;
    float sck[2][8], shk[2][8];
    #pragma unroll
    for (int kt = 0; kt < 2; ++kt)
        #pragma unroll
        for (int b = 0; b < 8; ++b) {
            int k = kt * 32 + (lane >> 4) * 8 + b;
            float scv = 1.f, shv = 0.f;
            if (applyBN) {
                float m = statsPrev[k * 32] * (1.f / N_NODES);
                float v = statsPrev[(64 + k) * 32] * (1.f / N_NODES) - m * m;
                scv = rsqrtf(v + BN_EPS) * gammaP[k];
                shv = betaP[k] - m * scv;
            }
            sck[kt][b] = scv;
            shk[kt][b] = shv;
        }
    float bAs[4], bPs[4];
    #pragma unroll
    for (int jt = 0; jt < 4; ++jt) {
        bAs[jt] = bsig[jt * 16 + col] * LOG2E;
        bPs[jt] = bsp[jt * 16 + col] * LOG2E;
    }
    const int wid = blockIdx.x * 4 + (threadIdx.x >> 6);
    const int nw = gridDim.x * 4;
    for (int c = wid; c < N_NODES / 16; c += nw) {
        const int node = c * 16 + col;
        const float4* Arow = (const float4*)(A + (size_t)node * HID);
        f16x8 af[2];
        #pragma unroll
        for (int kt = 0; kt < 2; ++kt) {
            float4 v0 = Arow[kt * 8 + (lane >> 4) * 2];
            float4 v1 = Arow[kt * 8 + (lane >> 4) * 2 + 1];
            float e0 = v0.x * sck[kt][0] + shk[kt][0];
            float e1 = v0.y * sck[kt][1] + shk[kt][1];
            float e2 = v0.z * sck[kt][2] + shk[kt][2];
            float e3 = v0.w * sck[kt][3] + shk[kt][3];
            float e4 = v1.x * sck[kt][4] + shk[kt][4];
            float e5 = v1.y * sck[kt][5] + shk[kt][5];
            float e6 = v1.z * sck[kt][6] + shk[kt][6];
            float e7 = v1.w * sck[kt][7] + shk[kt][7];
            af[kt] = f16x8{(f16)e0, (f16)e1, (f16)e2, (f16)e3,
                           (f16)e4, (f16)e5, (f16)e6, (f16)e7};
        }
        #pragma unroll
        for (int h = 0; h < 2; ++h) {
            f32x4 c4[8];
            #pragma unroll
            for (int jt2 = 0; jt2 < 8; ++jt2) {
                int jt = h * 8 + jt2;
                f32x4 acc = {};
                acc = __builtin_amdgcn_mfma_f32_16x16x32_f16(af[0], Wl[(0 * 16 + jt) * 64 + lane], acc, 0, 0, 0);
                c4[jt2] = __builtin_amdgcn_mfma_f32_16x16x32_f16(af[1], Wl[(1 * 16 + jt) * 64 + lane], acc, 0, 0, 0);
            }
            u32* dstArr = h ? pB : pA;
            #pragma unroll
            for (int jt2 = 0; jt2 < 4; ++jt2)
                #pragma unroll
                for (int r = 0; r < 4; ++r) {
                    float s = fmaf(c4[jt2][r], LOG2E, h ? 0.f : bAs[jt2]);
                    float p = fmaf(c4[jt2 + 4][r], LOG2E, h ? 0.f : bPs[jt2]);
                    int n2 = c * 16 + (lane >> 4) * 4 + r;
                    dstArr[(size_t)n2 * HID + jt2 * 16 + col] = f2bf(s) | (f2bf(p) << 16);
                }
        }
    }
}

// ---------------- nodeagg: dual-context, R8 dword gathers, shared jt weights -
#define CTX_DECL_INIT(S, widx)                                                \
    int n##S = __builtin_amdgcn_readfirstlane(partW[widx]);                   \
    const int ne##S = __builtin_amdgcn_readfirstlane(partW[(widx) + 1]);      \
    bool act##S = n##S < ne##S;                                               \
    int rb##S = 0, re##S = 0;                                                 \
    float resid##S = 0.f;                                                     \
    float bsg##S[4], bsp##S[4], accv##S[4];                                   \
    int s0##S = 0, s1##S = 0, s2##S = 0, s3##S = 0;                           \
    {                                                                         \
        _Pragma("unroll")                                                     \
        for (int jt = 0; jt < 4; ++jt) {                                      \
            bsg##S[jt] = 0.f; bsp##S[jt] = 0.f; accv##S[jt] = 0.f;            \
        }                                                                     \
        if (act##S) {                                                         \
            rb##S = __builtin_amdgcn_readfirstlane(rowptr[n##S]);             \
            re##S = __builtin_amdgcn_readfirstlane(rowptr[n##S + 1]);         \
            resid##S = A[(size_t)n##S * HID + lane];                          \
            if (applyBN) resid##S = resid##S * scL + shL;                     \
            _Pragma("unroll")                                                 \
            for (int jt = 0; jt < 4; ++jt) {                                  \
                u32 pb = pBv[(size_t)n##S * HID + jt * 16 + col];             \
                bsg##S[jt] = __uint_as_float(pb << 16);                       \
                bsp##S[jt] = __uint_as_float(pb & 0xffff0000u);               \
            }                                                                 \
            const int* sp = srcS + rb##S + rowb;                              \
            s0##S = sp[0]; s1##S = sp[1]; s2##S = sp[2]; s3##S = sp[3];       \
        }                                                                     \
    }

#define STEP_LOADS(S)                                                         \
    u32 ga##S[4][4];                                                          \
    f16x8 a0##S, a1##S;                                                       \
    if (act##S) {                                                             \
        const u32* g0##S = pAv + (size_t)s0##S * HID + col;                   \
        const u32* g1##S = pAv + (size_t)s1##S * HID + col;                   \
        const u32* g2##S = pAv + (size_t)s2##S * HID + col;                   \
        const u32* g3##S = pAv + (size_t)s3##S * HID + col;                   \
        _Pragma("unroll")                                                     \
        for (int jt = 0; jt < 4; ++jt) {                                      \
            ga##S[jt][0] = g0##S[jt * 16];                                    \
            ga##S[jt][1] = g1##S[jt * 16];                                    \
            ga##S[jt][2] = g2##S[jt * 16];                                    \
            ga##S[jt][3] = g3##S[jt * 16];                                    \
        }                                                                     \
        const f16x8* arow##S = (const f16x8*)(eapS + (size_t)(rb##S + col) * ROW_U32); \
        a0##S = arow##S[grp];                                                 \
        a1##S = arow##S[4 + grp];                                             \
    }

#define CTX_JT(S, jt)                                                         \
    if (act##S) {                                                             \
        f32x4 cs = {bsg##S[jt], bsg##S[jt], bsg##S[jt], bsg##S[jt]};          \
        f32x4 cp = {bsp##S[jt], bsp##S[jt], bsp##S[jt], bsp##S[jt]};          \
        cs = __builtin_amdgcn_mfma_f32_16x16x32_f16(a0##S, w0s, cs, 0, 0, 0); \
        cs = __builtin_amdgcn_mfma_f32_16x16x32_f16(a1##S, w1s, cs, 0, 0, 0); \
        cp = __builtin_amdgcn_mfma_f32_16x16x32_f16(a0##S, w0p, cp, 0, 0, 0); \
        cp = __builtin_amdgcn_mfma_f32_16x16x32_f16(a1##S, w1p, cp, 0, 0, 0); \
        const int cnt = re##S - rb##S;                                        \
        _Pragma("unroll")                                                     \
        for (int r = 0; r < 4; ++r) {                                         \
            u32 gw = ga##S[jt][r];                                            \
            float s_ = cs[r] + __uint_as_float(gw << 16);                     \
            float p_ = cp[r] + __uint_as_float(gw & 0xffff0000u);             \
            float g_ = __builtin_amdgcn_rcpf(1.f + exp2f(-s_));               \
            float m_ = fmaxf(p_, 0.f) + log2f(1.f + exp2f(-fabsf(p_)));       \
            accv##S[jt] += (rowb + r < cnt) ? g_ * m_ : 0.f;                  \
        }                                                                     \
    }

#define CTX_ADVANCE(S)                                                        \
    if (act##S) {                                                             \
        rb##S += 16;                                                          \
        while (rb##S >= re##S) {                                              \
            _Pragma("unroll")                                                 \
            for (int jt = 0; jt < 4; ++jt) {                                  \
                accv##S[jt] += __shfl_xor(accv##S[jt], 16);                   \
                accv##S[jt] += __shfl_xor(accv##S[jt], 32);                   \
            }                                                                 \
            float accSel = (lane & 32) ? ((lane & 16) ? accv##S[3] : accv##S[2]) \
                                       : ((lane & 16) ? accv##S[1] : accv##S[0]); \
            float outv = resid##S + accSel * LN2;                             \
            Aout[(size_t)n##S * HID + lane] = outv;                           \
            lsum += outv;                                                     \
            lsq += outv * outv;                                               \
            accv##S[0] = accv##S[1] = accv##S[2] = accv##S[3] = 0.f;          \
            rb##S = re##S;                                                    \
            ++n##S;                                                           \
            if (n##S >= ne##S) { act##S = false; break; }                     \
            re##S = __builtin_amdgcn_readfirstlane(rowptr[n##S + 1]);         \
            resid##S = A[(size_t)n##S * HID + lane];                          \
            if (applyBN) resid##S = resid##S * scL + shL;                     \
            _Pragma("unroll")                                                 \
            for (int jt = 0; jt < 4; ++jt) {                                  \
                u32 pb = pBv[(size_t)n##S * HID + jt * 16 + col];             \
                bsg##S[jt] = __uint_as_float(pb << 16);                       \
                bsp##S[jt] = __uint_as_float(pb & 0xffff0000u);               \
            }                                                                 \
        }                                                                     \
        if (act##S) {                                                         \
            const int* sp##S = srcS + rb##S + rowb;                           \
            s0##S = sp##S[0]; s1##S = sp##S[1];                               \
            s2##S = sp##S[2]; s3##S = sp##S[3];                               \
        }                                                                     \
    }

__global__ __launch_bounds__(256, 4) void k_nodeagg(const float* __restrict__ A,
                                                    const float* __restrict__ statsPrev,
                                                    const float* __restrict__ gammaP,
                                                    const float* __restrict__ betaP,
                                                    int applyBN,
                                                    const u32* __restrict__ pAv,
                                                    const u32* __restrict__ pBv,
                                                    const u32* __restrict__ eapS,
                                                    const int* __restrict__ srcS,
                                                    const int* __restrict__ rowptr,
                                                    const int* __restrict__ partW,
                                                    const f16* __restrict__ Wf16L,
                                                    float* __restrict__ Aout,
                                                    float* __restrict__ statsOut) {
    __shared__ f16x8 Wlds[16 * 64];   // 16 KB B-fragments
    __shared__ float redS[256], redQ[256];
    for (int i = threadIdx.x; i < 16 * 64; i += 256)
        Wlds[i] = ((const f16x8*)Wf16L)[i];

    const int lane = threadIdx.x & 63;
    const int col = lane & 15;
    const int grp = lane >> 4;
    const int rowb = grp * 4;

    float scL = 1.f, shL = 0.f;
    if (applyBN) {
        float m = statsPrev[lane * 32] * (1.f / N_NODES);
        float v = statsPrev[(64 + lane) * 32] * (1.f / N_NODES) - m * m;
        scL = rsqrtf(v + BN_EPS) * gammaP[lane];
        shL = betaP[lane] - m * scL;
    }
    __syncthreads();

    const int w2 = (((blockIdx.x << 2) + (threadIdx.x >> 6)) << 1);
    float lsum = 0.f, lsq = 0.f;

    CTX_DECL_INIT(A, w2)
    CTX_DECL_INIT(B, w2 + 1)

    while (actA || actB) {
        STEP_LOADS(A)
        STEP_LOADS(B)
        #pragma unroll
        for (int jt = 0; jt < 4; ++jt) {
            f16x8 w0s = Wlds[jt * 64 + lane];
            f16x8 w1s = Wlds[(8 + jt) * 64 + lane];
            f16x8 w0p = Wlds[(4 + jt) * 64 + lane];
            f16x8 w1p = Wlds[(12 + jt) * 64 + lane];
            CTX_JT(A, jt)
            CTX_JT(B, jt)
        }
        CTX_ADVANCE(A)
        CTX_ADVANCE(B)
    }

    redS[threadIdx.x] = lsum;
    redQ[threadIdx.x] = lsq;
    __syncthreads();
    if (threadIdx.x < 64) {
        float s = redS[threadIdx.x] + redS[threadIdx.x + 64] + redS[threadIdx.x + 128] + redS[threadIdx.x + 192];
        float q = redQ[threadIdx.x] + redQ[threadIdx.x + 64] + redQ[threadIdx.x + 128] + redQ[threadIdx.x + 192];
        unsafeAtomicAdd(&statsOut[threadIdx.x * 32], s);
        unsafeAtomicAdd(&statsOut[(64 + threadIdx.x) * 32], q);
    }
}

// ---------------- poolout: per-graph sum + final BN + 2-layer readout --------
__global__ __launch_bounds__(256) void k_poolout(const float* __restrict__ A,
                                                 const float* __restrict__ stats,
                                                 const float* __restrict__ gamma,
                                                 const float* __restrict__ beta,
                                                 const int* __restrict__ gstart,
                                                 const float* __restrict__ Wfc,
                                                 const float* __restrict__ bfc,
                                                 const float* __restrict__ Wout,
                                                 const float* __restrict__ bout,
                                                 float* __restrict__ out) {
    const int g = blockIdx.x;
    const int lane = threadIdx.x & 63;
    const int wv = threadIdx.x >> 6;
    const int rb = gstart[g], re = gstart[g + 1];
    float s = 0.f;
    for (int r = rb + wv; r < re; r += 4) s += A[(size_t)r * HID + lane];
    __shared__ float red[4][64];
    __shared__ float gfeat[64];
    red[wv][lane] = s;
    __syncthreads();
    if (threadIdx.x < 64) {
        float t = red[0][lane] + red[1][lane] + red[2][lane] + red[3][lane];
        float m = stats[lane * 32] * (1.f / N_NODES);
        float v = stats[(64 + lane) * 32] * (1.f / N_NODES) - m * m;
        float scv = rsqrtf(v + BN_EPS) * gamma[lane];
        float shv = beta[lane] - m * scv;
        gfeat[lane] = scv * t + shv * (float)(re - rb);
    }
    __syncthreads();
    __shared__ float r2[128];
    if (threadIdx.x < 128) {
        float p = bfc[threadIdx.x];
        #pragma unroll 8
        for (int k = 0; k < 64; ++k) p += gfeat[k] * Wfc[k * PRED + threadIdx.x];
        r2[threadIdx.x] = p * Wout[threadIdx.x];
    }
    __syncthreads();
    if (threadIdx.x < 64) {
        float v2 = r2[threadIdx.x] + r2[threadIdx.x + 64];
        #pragma unroll
        for (int off = 32; off > 0; off >>= 1) v2 += __shfl_down(v2, off);
        if (threadIdx.x == 0) out[g] = v2 + bout[0];
    }
}

extern "C" void kernel_launch(void* const* d_in, const int* in_sizes, int n_in,
                              void* d_out, int out_size, void* d_ws, size_t ws_size,
                              hipStream_t stream) {
    const float* x         = (const float*)d_in[0];
    const float* edge_attr = (const float*)d_in[1];
    const int*   src       = (const int*)d_in[2];
    const int*   dst       = (const int*)d_in[3];
    const int*   gidx      = (const int*)d_in[4];
    const float* W_embed   = (const float*)d_in[6];
    const float* b_embed   = (const float*)d_in[7];
    const float* W_sig     = (const float*)d_in[8];
    const float* b_sig     = (const float*)d_in[9];
    const float* W_sp      = (const float*)d_in[10];
    const float* b_sp      = (const float*)d_in[11];
    const float* bn_gamma  = (const float*)d_in[12];
    const float* bn_beta   = (const float*)d_in[13];
    const float* W_fc      = (const float*)d_in[14];
    const float* b_fc      = (const float*)d_in[15];
    const float* W_out     = (const float*)d_in[16];
    const float* b_out     = (const float*)d_in[17];
    float* out = (float*)d_out;

    const size_t NH = (size_t)N_NODES * HID;
    float* ws     = (float*)d_ws;
    float* A      = ws;                                   // NH f32
    u32*   pA     = (u32*)(A + NH);                       // NH u32, layout [n][jt*16+col]
    u32*   pB     = pA + NH;                              // NH u32
    u32*   eapS   = pB + NH;                              // (E+32)*24 u32
    int*   srcS   = (int*)(eapS + (size_t)(N_EDGES + 32) * ROW_U32);  // E+32
    int*   iperm  = srcS + N_EDGES + 32;                  // E
    int*   rowptr = iperm + N_EDGES;                      // N+1
    int*   deg    = rowptr + N_NODES + 1;                 // N (+ cursor N, zeroed together)
    int*   cursor = deg + N_NODES;                        // N
    int*   partial    = cursor + N_NODES;                 // 256
    int*   partialExc = partial + 256;                    // 256
    int*   partW  = partialExc + 256;                     // NW2+1
    int*   gstart = partW + NW2 + 2;                      // 501
    f16*   Wf16   = (f16*)(((size_t)(gstart + 504) + 15) & ~(size_t)15);  // 16B-aligned
    f16*   Wp2    = Wf16 + 3 * 2 * 8 * 64 * 8;
    f16*   Wef    = Wp2 + 3 * 2 * 16 * 64 * 8;
    float* stats  = (float*)(Wef + 3 * 4 * 64 * 8);       // 3 * 4096 f32

    // ---- prep (weights, zeros, gstart), CSR, partition ----
    k_prep<<<(10485 + 2 * N_NODES + 255) / 256, 256, 0, stream>>>(
        W_sig, W_sp, W_embed, gidx, Wf16, Wp2, Wef, gstart, deg);
    k_hist<<<(N_EDGES + 255) / 256, 256, 0, stream>>>(dst, deg);
    k_scanA<<<SCAN_BLOCKS, 256, 0, stream>>>(deg, partial);
    k_scanB<<<1, 256, 0, stream>>>(partial, partialExc, rowptr);
    k_scanC<<<SCAN_BLOCKS, 256, 0, stream>>>(deg, partialExc, rowptr);
    k_rank<<<(N_EDGES + 32 + 255) / 256, 256, 0, stream>>>(dst, src, rowptr, cursor,
                                                           srcS, iperm, partW);
    k_embedm<<<512, 256, 0, stream>>>(x, Wef, b_embed, A);
    k_epackS<<<4096, 256, 0, stream>>>(edge_attr, iperm, eapS);

    for (int i = 0; i < 3; ++i) {
        const float* stPrev = stats + (size_t)(i > 0 ? i - 1 : 0) * 4096;
        const float* gP     = bn_gamma + (i > 0 ? i - 1 : 0) * HID;
        const float* bP     = bn_beta + (i > 0 ? i - 1 : 0) * HID;
        float* stOut        = stats + (size_t)i * 4096;
        int applyBN = (i > 0) ? 1 : 0;
        k_projm<<<512, 256, 0, stream>>>(A, stPrev, gP, bP, applyBN,
                                         Wp2 + (size_t)i * 2 * 16 * 64 * 8,
                                         b_sig + i * HID, b_sp + i * HID,
                                         pA, pB, stOut);
        k_nodeagg<<<NAGG_BLOCKS, 256, 0, stream>>>(A, stPrev, gP, bP, applyBN,
                                                   pA, pB, eapS, srcS, rowptr, partW,
                                                   Wf16 + (size_t)i * 2 * 8 * 64 * 8,
                                                   A, stOut);
    }

    k_poolout<<<N_GRAPHS, 256, 0, stream>>>(A, stats + 2 * 4096, bn_gamma + 2 * HID,
                                            bn_beta + 2 * HID, gstart,
                                            W_fc, b_fc, W_out, b_out, out);
}

// Round 11
// 502.816 us; speedup vs baseline: 1.6032x; 1.6032x over previous
//
#include <hip/hip_runtime.h>

#define N_NODES 50000
#define N_EDGES 600000
#define N_GRAPHS 500
#define IN_F 92
#define HID 64
#define EDGE_F 41
#define ZDIM 169
#define PRED 128
#define BN_EPS 1e-5f
#define SCAN_BLOCKS 196          // ceil(50000/256)
#define ROW_U32 24               // eapS row = 48 f16 = 96 B
#define LOG2E 1.4426950408889634f
#define LN2   0.6931471805599453f
#define NAGG_BLOCKS 2048
#define NW2 (NAGG_BLOCKS * 8)    // 4 waves/block x 2 contexts
#define PART_T ((N_EDGES + 1 + NW2 - 1) / NW2)

typedef unsigned int u32;
typedef _Float16 f16;
typedef _Float16 f16x2 __attribute__((ext_vector_type(2)));
typedef _Float16 f16x8 __attribute__((ext_vector_type(8)));
typedef float f32x4 __attribute__((ext_vector_type(4)));

__device__ __forceinline__ u32 f2bf(float f) {
    u32 u = __float_as_uint(f);
    return (u + 0x7fffu + ((u >> 16) & 1u)) >> 16;
}

// first idx in [0, nelem) with a[idx] >= val (a sorted ascending)
__device__ __forceinline__ int lbound(const int* __restrict__ a, int nelem, int val) {
    int lo = 0, hi = nelem;
    while (lo < hi) {
        int m = (lo + hi) >> 1;
        if (a[m] < val) lo = m + 1; else hi = m;
    }
    return lo;
}

// ---------------- prep: all weight prep + zeroing + graph starts -------------
__global__ void k_prep(const float* __restrict__ Wsig, const float* __restrict__ Wsp,
                       const float* __restrict__ Wemb, const int* __restrict__ gidx,
                       f16* __restrict__ Wf16, f16* __restrict__ Wp2,
                       f16* __restrict__ Wef, int* __restrict__ gstart,
                       int* __restrict__ zeroBase) {
    int t = blockIdx.x * 256 + threadIdx.x;
    if (t < 3072) {
        int lane = t & 63;
        int jt = (t >> 6) & 7;
        int kt = (t >> 9) & 1;
        int L = t >> 10;
        int j128 = jt * 16 + (lane & 15);
        const float* Wbase = (j128 < 64) ? Wsig : Wsp;
        int j = j128 & 63;
        f16x8 v;
        #pragma unroll
        for (int b = 0; b < 8; ++b) {
            int k = kt * 32 + (lane >> 4) * 8 + b;
            float f = (k < EDGE_F) ? Wbase[(size_t)L * ZDIM * HID + (128 + k) * HID + j] * LOG2E : 0.f;
            v[b] = (f16)f;
        }
        *(f16x8*)(Wf16 + ((size_t)((L * 2 + kt) * 8 + jt) * 64 + lane) * 8) = v;
    } else if (t < 9216) {
        int t2 = t - 3072;
        int lane = t2 & 63;
        int jt = (t2 >> 6) & 15;
        int kt = (t2 >> 10) & 1;
        int L = t2 >> 11;
        int j256 = jt * 16 + (lane & 15);
        const float* Wbase = (j256 & 64) ? Wsp : Wsig;
        int rowoff = (j256 & 128) ? 64 : 0;
        int j = j256 & 63;
        f16x8 v;
        #pragma unroll
        for (int b = 0; b < 8; ++b) {
            int k = kt * 32 + (lane >> 4) * 8 + b;
            v[b] = (f16)Wbase[(size_t)L * ZDIM * HID + (rowoff + k) * HID + j];
        }
        *(f16x8*)(Wp2 + ((size_t)((L * 2 + kt) * 16 + jt) * 64 + lane) * 8) = v;
    } else if (t < 9984) {
        int t3 = t - 9216;
        int lane = t3 & 63;
        int jt = (t3 >> 6) & 3;
        int kt = t3 >> 8;    // 0..2
        int j = jt * 16 + (lane & 15);
        f16x8 v;
        #pragma unroll
        for (int b = 0; b < 8; ++b) {
            int k = kt * 32 + (lane >> 4) * 8 + b;
            v[b] = (k < IN_F) ? (f16)Wemb[(size_t)k * HID + j] : (f16)0.f;
        }
        *(f16x8*)(Wef + ((size_t)(kt * 4 + jt) * 64 + lane) * 8) = v;
    } else if (t < 10485) {
        int g = t - 9984;    // 0..500
        gstart[g] = lbound(gidx, N_NODES, g);
    } else if (t < 10485 + 2 * N_NODES) {
        zeroBase[t - 10485] = 0;
    }
}

__global__ void k_hist(const int* __restrict__ dst, int* __restrict__ deg) {
    int e = blockIdx.x * 256 + threadIdx.x;
    if (e < N_EDGES) atomicAdd(&deg[dst[e]], 1);
}

__global__ __launch_bounds__(256) void k_scanA(const int* __restrict__ deg,
                                               int* __restrict__ partial) {
    __shared__ int s[256];
    int i = blockIdx.x * 256 + threadIdx.x;
    s[threadIdx.x] = (i < N_NODES) ? deg[i] : 0;
    __syncthreads();
    for (int off = 128; off > 0; off >>= 1) {
        if (threadIdx.x < off) s[threadIdx.x] += s[threadIdx.x + off];
        __syncthreads();
    }
    if (threadIdx.x == 0) partial[blockIdx.x] = s[0];
}

__global__ __launch_bounds__(256) void k_scanB(const int* __restrict__ partial,
                                               int* __restrict__ partialExc,
                                               int* __restrict__ rowptr) {
    __shared__ int s[256];
    int t = threadIdx.x;
    int v = (t < SCAN_BLOCKS) ? partial[t] : 0;
    s[t] = v;
    __syncthreads();
    for (int off = 1; off < 256; off <<= 1) {
        int x = (t >= off) ? s[t - off] : 0;
        __syncthreads();
        s[t] += x;
        __syncthreads();
    }
    partialExc[t] = s[t] - v;
    if (t == 0) rowptr[N_NODES] = N_EDGES;
}

__global__ __launch_bounds__(256) void k_scanC(const int* __restrict__ deg,
                                               const int* __restrict__ partialExc,
                                               int* __restrict__ rowptr) {
    __shared__ int s[256];
    int i = blockIdx.x * 256 + threadIdx.x;
    int t = threadIdx.x;
    int v = (i < N_NODES) ? deg[i] : 0;
    s[t] = v;
    __syncthreads();
    for (int off = 1; off < 256; off <<= 1) {
        int x = (t >= off) ? s[t - off] : 0;
        __syncthreads();
        s[t] += x;
        __syncthreads();
    }
    if (i < N_NODES) rowptr[i] = s[t] - v + partialExc[blockIdx.x];
}

// ---------------- rank: CSR slot assignment + wave partition -----------------
__global__ void k_rank(const int* __restrict__ dst, const int* __restrict__ src,
                       const int* __restrict__ rowptr, int* __restrict__ cursor,
                       int* __restrict__ srcS, int* __restrict__ iperm,
                       int* __restrict__ partW) {
    int e = blockIdx.x * 256 + threadIdx.x;
    if (e <= NW2) partW[e] = min(lbound(rowptr, N_NODES + 1, e * PART_T), N_NODES);
    if (e >= N_EDGES) {
        if (e < N_EDGES + 32) srcS[e] = 0;   // pad: prefetch reads stay in-bounds
        return;
    }
    int d = dst[e];
    int p = rowptr[d] + atomicAdd(&cursor[d], 1);
    srcS[p] = src[e];
    iperm[p] = e;
}

// ---------------- epackS: gather-permute ea rows -> f16, 96 B rows ----------
__global__ __launch_bounds__(256) void k_epackS(const float* __restrict__ ea,
                                                const int* __restrict__ iperm,
                                                u32* __restrict__ eapS) {
    const int total = N_EDGES * ROW_U32;
    const int stride = gridDim.x * 256;
    for (int idx = blockIdx.x * 256 + threadIdx.x; idx < total; idx += stride) {
        int p = idx / ROW_U32;
        int q = idx - p * ROW_U32;
        int e = iperm[p];
        int k0 = 2 * q, k1 = k0 + 1;
        float f0 = (k0 < EDGE_F) ? ea[(size_t)e * EDGE_F + k0] : 0.f;
        float f1 = (k1 < EDGE_F) ? ea[(size_t)e * EDGE_F + k1] : 0.f;
        f16x2 hv = {(f16)f0, (f16)f1};
        eapS[idx] = __builtin_bit_cast(u32, hv);
    }
}

// ---------------- embedm: A = x @ W_embed + b via MFMA ----------------------
__global__ __launch_bounds__(256) void k_embedm(const float* __restrict__ x,
                                                const f16* __restrict__ Wef,
                                                const float* __restrict__ b,
                                                float* __restrict__ A) {
    __shared__ f16x8 Wl[12 * 64];   // 12 KB
    for (int i = threadIdx.x; i < 12 * 64; i += 256) Wl[i] = ((const f16x8*)Wef)[i];
    __syncthreads();
    const int lane = threadIdx.x & 63;
    const int col = lane & 15, grp = lane >> 4;
    float bj[4];
    #pragma unroll
    for (int jt = 0; jt < 4; ++jt) bj[jt] = b[jt * 16 + col];
    const int wid = blockIdx.x * 4 + (threadIdx.x >> 6);
    const int nw = gridDim.x * 4;
    for (int c = wid; c < N_NODES / 16; c += nw) {
        const int node = c * 16 + col;
        const float* xr = x + (size_t)node * IN_F;
        f16x8 af[3];
        #pragma unroll
        for (int kt = 0; kt < 3; ++kt) {
            int base = kt * 32 + grp * 8;
            float4 v0 = *(const float4*)(xr + base);
            float4 v1 = (base + 4 < IN_F) ? *(const float4*)(xr + base + 4)
                                          : make_float4(0.f, 0.f, 0.f, 0.f);
            af[kt] = f16x8{(f16)v0.x, (f16)v0.y, (f16)v0.z, (f16)v0.w,
                           (f16)v1.x, (f16)v1.y, (f16)v1.z, (f16)v1.w};
        }
        #pragma unroll
        for (int jt = 0; jt < 4; ++jt) {
            f32x4 c4 = {};
            c4 = __builtin_amdgcn_mfma_f32_16x16x32_f16(af[0], Wl[(0 * 4 + jt) * 64 + lane], c4, 0, 0, 0);
            c4 = __builtin_amdgcn_mfma_f32_16x16x32_f16(af[1], Wl[(1 * 4 + jt) * 64 + lane], c4, 0, 0, 0);
            c4 = __builtin_amdgcn_mfma_f32_16x16x32_f16(af[2], Wl[(2 * 4 + jt) * 64 + lane], c4, 0, 0, 0);
            #pragma unroll
            for (int r = 0; r < 4; ++r)
                A[(size_t)(c * 16 + grp * 4 + r) * HID + jt * 16 + col] = c4[r] + bj[jt];
        }
    }
}

// ---------------- projm: MFMA node projections (R8 layout: [n][jt*16+col]) ---
__global__ __launch_bounds__(256, 4) void k_projm(const float* __restrict__ A,
                                                  const float* __restrict__ statsPrev,
                                                  const float* __restrict__ gammaP,
                                                  const float* __restrict__ betaP,
                                                  int applyBN,
                                                  const f16* __restrict__ Wp2L,
                                                  const float* __restrict__ bsig,
                                                  const float* __restrict__ bsp,
                                                  u32* __restrict__ pA,
                                                  u32* __restrict__ pB,
                                                  float* __restrict__ statsOut) {
    __shared__ f16x8 Wl[32 * 64];   // 32 KB
    for (int i = threadIdx.x; i < 32 * 64; i += 256) Wl[i] = ((const f16x8*)Wp2L)[i];
    if (blockIdx.x == 0)
        for (int i = threadIdx.x; i < 128 * 32; i += 256) statsOut[i] = 0.f;
    __syncthreads();
    const int lane = threadIdx.x & 63;
    const int col = lane & 15;
    float sck[2][8], shk[2][8];
    #pragma unroll
    for (int kt = 0; kt < 2; ++kt)
        #pragma unroll
        for (int b = 0; b < 8; ++b) {
            int k = kt * 32 + (lane >> 4) * 8 + b;
            float scv = 1.f, shv = 0.f;
            if (applyBN) {
                float m = statsPrev[k * 32] * (1.f / N_NODES);
                float v = statsPrev[(64 + k) * 32] * (1.f / N_NODES) - m * m;
                scv = rsqrtf(v + BN_EPS) * gammaP[k];
                shv = betaP[k] - m * scv;
            }
            sck[kt][b] = scv;
            shk[kt][b] = shv;
        }
    float bAs[4], bPs[4];
    #pragma unroll
    for (int jt = 0; jt < 4; ++jt) {
        bAs[jt] = bsig[jt * 16 + col] * LOG2E;
        bPs[jt] = bsp[jt * 16 + col] * LOG2E;
    }
    const int wid = blockIdx.x * 4 + (threadIdx.x >> 6);
    const int nw = gridDim.x * 4;
    for (int c = wid; c < N_NODES / 16; c += nw) {
        const int node = c * 16 + col;
        const float4* Arow = (const float4*)(A + (size_t)node * HID);
        f16x8 af[2];
        #pragma unroll
        for (int kt = 0; kt < 2; ++kt) {
            float4 v0 = Arow[kt * 8 + (lane >> 4) * 2];
            float4 v1 = Arow[kt * 8 + (lane >> 4) * 2 + 1];
            float e0 = v0.x * sck[kt][0] + shk[kt][0];
            float e1 = v0.y * sck[kt][1] + shk[kt][1];
            float e2 = v0.z * sck[kt][2] + shk[kt][2];
            float e3 = v0.w * sck[kt][3] + shk[kt][3];
            float e4 = v1.x * sck[kt][4] + shk[kt][4];
            float e5 = v1.y * sck[kt][5] + shk[kt][5];
            float e6 = v1.z * sck[kt][6] + shk[kt][6];
            float e7 = v1.w * sck[kt][7] + shk[kt][7];
            af[kt] = f16x8{(f16)e0, (f16)e1, (f16)e2, (f16)e3,
                           (f16)e4, (f16)e5, (f16)e6, (f16)e7};
        }
        #pragma unroll
        for (int h = 0; h < 2; ++h) {
            f32x4 c4[8];
            #pragma unroll
            for (int jt2 = 0; jt2 < 8; ++jt2) {
                int jt = h * 8 + jt2;
                f32x4 acc = {};
                acc = __builtin_amdgcn_mfma_f32_16x16x32_f16(af[0], Wl[(0 * 16 + jt) * 64 + lane], acc, 0, 0, 0);
                c4[jt2] = __builtin_amdgcn_mfma_f32_16x16x32_f16(af[1], Wl[(1 * 16 + jt) * 64 + lane], acc, 0, 0, 0);
            }
            u32* dstArr = h ? pB : pA;
            #pragma unroll
            for (int jt2 = 0; jt2 < 4; ++jt2)
                #pragma unroll
                for (int r = 0; r < 4; ++r) {
                    float s = fmaf(c4[jt2][r], LOG2E, h ? 0.f : bAs[jt2]);
                    float p = fmaf(c4[jt2 + 4][r], LOG2E, h ? 0.f : bPs[jt2]);
                    int n2 = c * 16 + (lane >> 4) * 4 + r;
                    dstArr[(size_t)n2 * HID + jt2 * 16 + col] = f2bf(s) | (f2bf(p) << 16);
                }
        }
    }
}

// ---------------- nodeagg: R8-verbatim dual-context interleave ---------------
// Per-context STEP_COMPUTE (weights read inside) keeps each context's live
// state contained -> no spill. Do NOT share weight reads across contexts
// (R9/R10 regression: forces both contexts' tile state live -> scratch).

#define CTX_DECL_INIT(S, widx)                                                \
    int n##S = __builtin_amdgcn_readfirstlane(partW[widx]);                   \
    const int ne##S = __builtin_amdgcn_readfirstlane(partW[(widx) + 1]);      \
    bool act##S = n##S < ne##S;                                               \
    int rb##S = 0, re##S = 0;                                                 \
    float resid##S = 0.f;                                                     \
    float bsg##S[4], bsp##S[4], accv##S[4];                                   \
    int s0##S = 0, s1##S = 0, s2##S = 0, s3##S = 0;                           \
    {                                                                         \
        _Pragma("unroll")                                                     \
        for (int jt = 0; jt < 4; ++jt) {                                      \
            bsg##S[jt] = 0.f; bsp##S[jt] = 0.f; accv##S[jt] = 0.f;            \
        }                                                                     \
        if (act##S) {                                                         \
            rb##S = __builtin_amdgcn_readfirstlane(rowptr[n##S]);             \
            re##S = __builtin_amdgcn_readfirstlane(rowptr[n##S + 1]);         \
            resid##S = A[(size_t)n##S * HID + lane];                          \
            if (applyBN) resid##S = resid##S * scL + shL;                     \
            _Pragma("unroll")                                                 \
            for (int jt = 0; jt < 4; ++jt) {                                  \
                u32 pb = pBv[(size_t)n##S * HID + jt * 16 + col];             \
                bsg##S[jt] = __uint_as_float(pb << 16);                       \
                bsp##S[jt] = __uint_as_float(pb & 0xffff0000u);               \
            }                                                                 \
            const int* sp = srcS + rb##S + rowb;                              \
            s0##S = sp[0]; s1##S = sp[1]; s2##S = sp[2]; s3##S = sp[3];       \
        }                                                                     \
    }

#define STEP_LOADS(S)                                                         \
    u32 ga##S[4][4];                                                          \
    f16x8 a0##S, a1##S;                                                       \
    if (act##S) {                                                             \
        const u32* g0##S = pAv + (size_t)s0##S * HID + col;                   \
        const u32* g1##S = pAv + (size_t)s1##S * HID + col;                   \
        const u32* g2##S = pAv + (size_t)s2##S * HID + col;                   \
        const u32* g3##S = pAv + (size_t)s3##S * HID + col;                   \
        _Pragma("unroll")                                                     \
        for (int jt = 0; jt < 4; ++jt) {                                      \
            ga##S[jt][0] = g0##S[jt * 16];                                    \
            ga##S[jt][1] = g1##S[jt * 16];                                    \
            ga##S[jt][2] = g2##S[jt * 16];                                    \
            ga##S[jt][3] = g3##S[jt * 16];                                    \
        }                                                                     \
        const f16x8* arow##S = (const f16x8*)(eapS + (size_t)(rb##S + col) * ROW_U32); \
        a0##S = arow##S[grp];                                                 \
        a1##S = arow##S[4 + grp];                                             \
    }

#define STEP_COMPUTE(S)                                                       \
    if (act##S) {                                                             \
        const int cnt##S = re##S - rb##S;                                     \
        if (cnt##S > 0) {                                                     \
            _Pragma("unroll")                                                 \
            for (int jt = 0; jt < 4; ++jt) {                                  \
                f32x4 cs = {bsg##S[jt], bsg##S[jt], bsg##S[jt], bsg##S[jt]};  \
                f32x4 cp = {bsp##S[jt], bsp##S[jt], bsp##S[jt], bsp##S[jt]};  \
                f16x8 w0s = Wlds[(jt) * 64 + lane];                           \
                f16x8 w1s = Wlds[(8 + jt) * 64 + lane];                       \
                f16x8 w0p = Wlds[(4 + jt) * 64 + lane];                       \
                f16x8 w1p = Wlds[(12 + jt) * 64 + lane];                      \
                cs = __builtin_amdgcn_mfma_f32_16x16x32_f16(a0##S, w0s, cs, 0, 0, 0); \
                cs = __builtin_amdgcn_mfma_f32_16x16x32_f16(a1##S, w1s, cs, 0, 0, 0); \
                cp = __builtin_amdgcn_mfma_f32_16x16x32_f16(a0##S, w0p, cp, 0, 0, 0); \
                cp = __builtin_amdgcn_mfma_f32_16x16x32_f16(a1##S, w1p, cp, 0, 0, 0); \
                _Pragma("unroll")                                             \
                for (int r = 0; r < 4; ++r) {                                 \
                    float s_ = cs[r] + __uint_as_float(ga##S[jt][r] << 16);   \
                    float p_ = cp[r] + __uint_as_float(ga##S[jt][r] & 0xffff0000u); \
                    float g_ = __builtin_amdgcn_rcpf(1.f + exp2f(-s_));       \
                    float m_ = fmaxf(p_, 0.f) + log2f(1.f + exp2f(-fabsf(p_))); \
                    accv##S[jt] += (rowb + r < cnt##S) ? g_ * m_ : 0.f;       \
                }                                                             \
            }                                                                 \
            rb##S += 16;                                                      \
        }                                                                     \
        while (rb##S >= re##S) {                                              \
            _Pragma("unroll")                                                 \
            for (int jt = 0; jt < 4; ++jt) {                                  \
                accv##S[jt] += __shfl_xor(accv##S[jt], 16);                   \
                accv##S[jt] += __shfl_xor(accv##S[jt], 32);                   \
            }                                                                 \
            float accSel = (lane & 32) ? ((lane & 16) ? accv##S[3] : accv##S[2]) \
                                       : ((lane & 16) ? accv##S[1] : accv##S[0]); \
            float outv = resid##S + accSel * LN2;                             \
            Aout[(size_t)n##S * HID + lane] = outv;                           \
            lsum += outv;                                                     \
            lsq += outv * outv;                                               \
            accv##S[0] = accv##S[1] = accv##S[2] = accv##S[3] = 0.f;          \
            rb##S = re##S;                                                    \
            ++n##S;                                                           \
            if (n##S >= ne##S) { act##S = false; break; }                     \
            re##S = __builtin_amdgcn_readfirstlane(rowptr[n##S + 1]);         \
            resid##S = A[(size_t)n##S * HID + lane];                          \
            if (applyBN) resid##S = resid##S * scL + shL;                     \
            _Pragma("unroll")                                                 \
            for (int jt = 0; jt < 4; ++jt) {                                  \
                u32 pb = pBv[(size_t)n##S * HID + jt * 16 + col];             \
                bsg##S[jt] = __uint_as_float(pb << 16);                       \
                bsp##S[jt] = __uint_as_float(pb & 0xffff0000u);               \
            }                                                                 \
        }                                                                     \
        if (act##S) {                                                         \
            const int* sp##S = srcS + rb##S + rowb;                           \
            s0##S = sp##S[0]; s1##S = sp##S[1];                               \
            s2##S = sp##S[2]; s3##S = sp##S[3];                               \
        }                                                                     \
    }

__global__ __launch_bounds__(256, 4) void k_nodeagg(const float* __restrict__ A,
                                                    const float* __restrict__ statsPrev,
                                                    const float* __restrict__ gammaP,
                                                    const float* __restrict__ betaP,
                                                    int applyBN,
                                                    const u32* __restrict__ pAv,
                                                    const u32* __restrict__ pBv,
                                                    const u32* __restrict__ eapS,
                                                    const int* __restrict__ srcS,
                                                    const int* __restrict__ rowptr,
                                                    const int* __restrict__ partW,
                                                    const f16* __restrict__ Wf16L,
                                                    float* __restrict__ Aout,
                                                    float* __restrict__ statsOut) {
    __shared__ f16x8 Wlds[16 * 64];   // 16 KB B-fragments
    __shared__ float redS[256], redQ[256];
    for (int i = threadIdx.x; i < 16 * 64; i += 256)
        Wlds[i] = ((const f16x8*)Wf16L)[i];

    const int lane = threadIdx.x & 63;
    const int col = lane & 15;
    const int grp = lane >> 4;
    const int rowb = grp * 4;

    float scL = 1.f, shL = 0.f;
    if (applyBN) {
        float m = statsPrev[lane * 32] * (1.f / N_NODES);
        float v = statsPrev[(64 + lane) * 32] * (1.f / N_NODES) - m * m;
        scL = rsqrtf(v + BN_EPS) * gammaP[lane];
        shL = betaP[lane] - m * scL;
    }
    __syncthreads();

    const int w2 = (((blockIdx.x << 2) + (threadIdx.x >> 6)) << 1);
    float lsum = 0.f, lsq = 0.f;

    CTX_DECL_INIT(A, w2)
    CTX_DECL_INIT(B, w2 + 1)

    while (actA || actB) {
        STEP_LOADS(A)
        STEP_LOADS(B)
        STEP_COMPUTE(A)
        STEP_COMPUTE(B)
    }

    redS[threadIdx.x] = lsum;
    redQ[threadIdx.x] = lsq;
    __syncthreads();
    if (threadIdx.x < 64) {
        float s = redS[threadIdx.x] + redS[threadIdx.x + 64] + redS[threadIdx.x + 128] + redS[threadIdx.x + 192];
        float q = redQ[threadIdx.x] + redQ[threadIdx.x + 64] + redQ[threadIdx.x + 128] + redQ[threadIdx.x + 192];
        unsafeAtomicAdd(&statsOut[threadIdx.x * 32], s);
        unsafeAtomicAdd(&statsOut[(64 + threadIdx.x) * 32], q);
    }
}

// ---------------- poolout: per-graph sum + final BN + 2-layer readout --------
__global__ __launch_bounds__(256) void k_poolout(const float* __restrict__ A,
                                                 const float* __restrict__ stats,
                                                 const float* __restrict__ gamma,
                                                 const float* __restrict__ beta,
                                                 const int* __restrict__ gstart,
                                                 const float* __restrict__ Wfc,
                                                 const float* __restrict__ bfc,
                                                 const float* __restrict__ Wout,
                                                 const float* __restrict__ bout,
                                                 float* __restrict__ out) {
    const int g = blockIdx.x;
    const int lane = threadIdx.x & 63;
    const int wv = threadIdx.x >> 6;
    const int rb = gstart[g], re = gstart[g + 1];
    float s = 0.f;
    for (int r = rb + wv; r < re; r += 4) s += A[(size_t)r * HID + lane];
    __shared__ float red[4][64];
    __shared__ float gfeat[64];
    red[wv][lane] = s;
    __syncthreads();
    if (threadIdx.x < 64) {
        float t = red[0][lane] + red[1][lane] + red[2][lane] + red[3][lane];
        float m = stats[lane * 32] * (1.f / N_NODES);
        float v = stats[(64 + lane) * 32] * (1.f / N_NODES) - m * m;
        float scv = rsqrtf(v + BN_EPS) * gamma[lane];
        float shv = beta[lane] - m * scv;
        gfeat[lane] = scv * t + shv * (float)(re - rb);
    }
    __syncthreads();
    __shared__ float r2[128];
    if (threadIdx.x < 128) {
        float p = bfc[threadIdx.x];
        #pragma unroll 8
        for (int k = 0; k < 64; ++k) p += gfeat[k] * Wfc[k * PRED + threadIdx.x];
        r2[threadIdx.x] = p * Wout[threadIdx.x];
    }
    __syncthreads();
    if (threadIdx.x < 64) {
        float v2 = r2[threadIdx.x] + r2[threadIdx.x + 64];
        #pragma unroll
        for (int off = 32; off > 0; off >>= 1) v2 += __shfl_down(v2, off);
        if (threadIdx.x == 0) out[g] = v2 + bout[0];
    }
}

extern "C" void kernel_launch(void* const* d_in, const int* in_sizes, int n_in,
                              void* d_out, int out_size, void* d_ws, size_t ws_size,
                              hipStream_t stream) {
    const float* x         = (const float*)d_in[0];
    const float* edge_attr = (const float*)d_in[1];
    const int*   src       = (const int*)d_in[2];
    const int*   dst       = (const int*)d_in[3];
    const int*   gidx      = (const int*)d_in[4];
    const float* W_embed   = (const float*)d_in[6];
    const float* b_embed   = (const float*)d_in[7];
    const float* W_sig     = (const float*)d_in[8];
    const float* b_sig     = (const float*)d_in[9];
    const float* W_sp      = (const float*)d_in[10];
    const float* b_sp      = (const float*)d_in[11];
    const float* bn_gamma  = (const float*)d_in[12];
    const float* bn_beta   = (const float*)d_in[13];
    const float* W_fc      = (const float*)d_in[14];
    const float* b_fc      = (const float*)d_in[15];
    const float* W_out     = (const float*)d_in[16];
    const float* b_out     = (const float*)d_in[17];
    float* out = (float*)d_out;

    const size_t NH = (size_t)N_NODES * HID;
    float* ws     = (float*)d_ws;
    float* A      = ws;                                   // NH f32
    u32*   pA     = (u32*)(A + NH);                       // NH u32, layout [n][jt*16+col]
    u32*   pB     = pA + NH;                              // NH u32
    u32*   eapS   = pB + NH;                              // (E+32)*24 u32
    int*   srcS   = (int*)(eapS + (size_t)(N_EDGES + 32) * ROW_U32);  // E+32
    int*   iperm  = srcS + N_EDGES + 32;                  // E
    int*   rowptr = iperm + N_EDGES;                      // N+1
    int*   deg    = rowptr + N_NODES + 1;                 // N (+ cursor N, zeroed together)
    int*   cursor = deg + N_NODES;                        // N
    int*   partial    = cursor + N_NODES;                 // 256
    int*   partialExc = partial + 256;                    // 256
    int*   partW  = partialExc + 256;                     // NW2+1
    int*   gstart = partW + NW2 + 2;                      // 501
    f16*   Wf16   = (f16*)(((size_t)(gstart + 504) + 15) & ~(size_t)15);  // 16B-aligned
    f16*   Wp2    = Wf16 + 3 * 2 * 8 * 64 * 8;
    f16*   Wef    = Wp2 + 3 * 2 * 16 * 64 * 8;
    float* stats  = (float*)(Wef + 3 * 4 * 64 * 8);       // 3 * 4096 f32

    // ---- prep (weights, zeros, gstart), CSR, partition ----
    k_prep<<<(10485 + 2 * N_NODES + 255) / 256, 256, 0, stream>>>(
        W_sig, W_sp, W_embed, gidx, Wf16, Wp2, Wef, gstart, deg);
    k_hist<<<(N_EDGES + 255) / 256, 256, 0, stream>>>(dst, deg);
    k_scanA<<<SCAN_BLOCKS, 256, 0, stream>>>(deg, partial);
    k_scanB<<<1, 256, 0, stream>>>(partial, partialExc, rowptr);
    k_scanC<<<SCAN_BLOCKS, 256, 0, stream>>>(deg, partialExc, rowptr);
    k_rank<<<(N_EDGES + 32 + 255) / 256, 256, 0, stream>>>(dst, src, rowptr, cursor,
                                                           srcS, iperm, partW);
    k_embedm<<<512, 256, 0, stream>>>(x, Wef, b_embed, A);
    k_epackS<<<4096, 256, 0, stream>>>(edge_attr, iperm, eapS);

    for (int i = 0; i < 3; ++i) {
        const float* stPrev = stats + (size_t)(i > 0 ? i - 1 : 0) * 4096;
        const float* gP     = bn_gamma + (i > 0 ? i - 1 : 0) * HID;
        const float* bP     = bn_beta + (i > 0 ? i - 1 : 0) * HID;
        float* stOut        = stats + (size_t)i * 4096;
        int applyBN = (i > 0) ? 1 : 0;
        k_projm<<<512, 256, 0, stream>>>(A, stPrev, gP, bP, applyBN,
                                         Wp2 + (size_t)i * 2 * 16 * 64 * 8,
                                         b_sig + i * HID, b_sp + i * HID,
                                         pA, pB, stOut);
        k_nodeagg<<<NAGG_BLOCKS, 256, 0, stream>>>(A, stPrev, gP, bP, applyBN,
                                                   pA, pB, eapS, srcS, rowptr, partW,
                                                   Wf16 + (size_t)i * 2 * 8 * 64 * 8,
                                                   A, stOut);
    }

    k_poolout<<<N_GRAPHS, 256, 0, stream>>>(A, stats + 2 * 4096, bn_gamma + 2 * HID,
                                            bn_beta + 2 * HID, gstart,
                                            W_fc, b_fc, W_out, b_out, out);
}

// Round 12
// 477.224 us; speedup vs baseline: 1.6892x; 1.0536x over previous
//
#include <hip/hip_runtime.h>

#define N_NODES 50000
#define N_EDGES 600000
#define N_GRAPHS 500
#define IN_F 92
#define HID 64
#define EDGE_F 41
#define ZDIM 169
#define PRED 128
#define BN_EPS 1e-5f
#define SCAN_BLOCKS 196          // ceil(50000/256)
#define ROW_U32 24               // eapS row = 48 f16 = 96 B
#define LOG2E 1.4426950408889634f
#define LN2   0.6931471805599453f
#define NAGG_BLOCKS 2048
#define NW2 (NAGG_BLOCKS * 8)    // 4 waves/block x 2 contexts
#define PART_T ((N_EDGES + 1 + NW2 - 1) / NW2)

typedef unsigned int u32;
typedef _Float16 f16;
typedef _Float16 f16x2 __attribute__((ext_vector_type(2)));
typedef _Float16 f16x8 __attribute__((ext_vector_type(8)));
typedef float f32x4 __attribute__((ext_vector_type(4)));

__device__ __forceinline__ u32 f2bf(float f) {
    u32 u = __float_as_uint(f);
    return (u + 0x7fffu + ((u >> 16) & 1u)) >> 16;
}

// first idx in [0, nelem) with a[idx] >= val (a sorted ascending)
__device__ __forceinline__ int lbound(const int* __restrict__ a, int nelem, int val) {
    int lo = 0, hi = nelem;
    while (lo < hi) {
        int m = (lo + hi) >> 1;
        if (a[m] < val) lo = m + 1; else hi = m;
    }
    return lo;
}

// ---------------- prep: all weight prep + zeroing + graph starts -------------
__global__ void k_prep(const float* __restrict__ Wsig, const float* __restrict__ Wsp,
                       const float* __restrict__ Wemb, const int* __restrict__ gidx,
                       f16* __restrict__ Wf16, f16* __restrict__ Wp2,
                       f16* __restrict__ Wef, int* __restrict__ gstart,
                       int* __restrict__ rowptr, int* __restrict__ zeroBase) {
    int t = blockIdx.x * 256 + threadIdx.x;
    if (t < 3072) {
        int lane = t & 63;
        int jt = (t >> 6) & 7;
        int kt = (t >> 9) & 1;
        int L = t >> 10;
        int j128 = jt * 16 + (lane & 15);
        const float* Wbase = (j128 < 64) ? Wsig : Wsp;
        int j = j128 & 63;
        f16x8 v;
        #pragma unroll
        for (int b = 0; b < 8; ++b) {
            int k = kt * 32 + (lane >> 4) * 8 + b;
            float f = (k < EDGE_F) ? Wbase[(size_t)L * ZDIM * HID + (128 + k) * HID + j] * LOG2E : 0.f;
            v[b] = (f16)f;
        }
        *(f16x8*)(Wf16 + ((size_t)((L * 2 + kt) * 8 + jt) * 64 + lane) * 8) = v;
    } else if (t < 9216) {
        int t2 = t - 3072;
        int lane = t2 & 63;
        int jt = (t2 >> 6) & 15;
        int kt = (t2 >> 10) & 1;
        int L = t2 >> 11;
        int j256 = jt * 16 + (lane & 15);
        const float* Wbase = (j256 & 64) ? Wsp : Wsig;
        int rowoff = (j256 & 128) ? 64 : 0;
        int j = j256 & 63;
        f16x8 v;
        #pragma unroll
        for (int b = 0; b < 8; ++b) {
            int k = kt * 32 + (lane >> 4) * 8 + b;
            v[b] = (f16)Wbase[(size_t)L * ZDIM * HID + (rowoff + k) * HID + j];
        }
        *(f16x8*)(Wp2 + ((size_t)((L * 2 + kt) * 16 + jt) * 64 + lane) * 8) = v;
    } else if (t < 9984) {
        int t3 = t - 9216;
        int lane = t3 & 63;
        int jt = (t3 >> 6) & 3;
        int kt = t3 >> 8;    // 0..2
        int j = jt * 16 + (lane & 15);
        f16x8 v;
        #pragma unroll
        for (int b = 0; b < 8; ++b) {
            int k = kt * 32 + (lane >> 4) * 8 + b;
            v[b] = (k < IN_F) ? (f16)Wemb[(size_t)k * HID + j] : (f16)0.f;
        }
        *(f16x8*)(Wef + ((size_t)(kt * 4 + jt) * 64 + lane) * 8) = v;
    } else if (t < 10485) {
        int g = t - 9984;    // 0..500
        gstart[g] = lbound(gidx, N_NODES, g);
        if (g == 0) rowptr[N_NODES] = N_EDGES;
    } else if (t < 10485 + 2 * N_NODES) {
        zeroBase[t - 10485] = 0;
    }
}

__global__ void k_hist(const int* __restrict__ dst, int* __restrict__ deg) {
    int e = blockIdx.x * 256 + threadIdx.x;
    if (e < N_EDGES) atomicAdd(&deg[dst[e]], 1);
}

__global__ __launch_bounds__(256) void k_scanA(const int* __restrict__ deg,
                                               int* __restrict__ partial) {
    __shared__ int s[256];
    int i = blockIdx.x * 256 + threadIdx.x;
    s[threadIdx.x] = (i < N_NODES) ? deg[i] : 0;
    __syncthreads();
    for (int off = 128; off > 0; off >>= 1) {
        if (threadIdx.x < off) s[threadIdx.x] += s[threadIdx.x + off];
        __syncthreads();
    }
    if (threadIdx.x == 0) partial[blockIdx.x] = s[0];
}

// scanC with inline lookback over block partials (replaces scanB+scanC)
__global__ __launch_bounds__(256) void k_scanC(const int* __restrict__ deg,
                                               const int* __restrict__ partial,
                                               int* __restrict__ rowptr) {
    __shared__ int s[256];
    __shared__ int base;
    int i = blockIdx.x * 256 + threadIdx.x;
    int t = threadIdx.x;
    if (t < 64) {
        int acc = 0;
        for (int j = t; j < blockIdx.x; j += 64) acc += partial[j];
        #pragma unroll
        for (int off = 32; off > 0; off >>= 1) acc += __shfl_xor(acc, off);
        if (t == 0) base = acc;
    }
    int v = (i < N_NODES) ? deg[i] : 0;
    s[t] = v;
    __syncthreads();
    for (int off = 1; off < 256; off <<= 1) {
        int x = (t >= off) ? s[t - off] : 0;
        __syncthreads();
        s[t] += x;
        __syncthreads();
    }
    if (i < N_NODES) rowptr[i] = s[t] - v + base;
}

// ---------------- rank: CSR slot + fused f16 edge pack + wave partition ------
__global__ void k_rank(const int* __restrict__ dst, const int* __restrict__ src,
                       const float* __restrict__ ea,
                       const int* __restrict__ rowptr, int* __restrict__ cursor,
                       int* __restrict__ srcS, u32* __restrict__ eapS,
                       int* __restrict__ partW) {
    int e = blockIdx.x * 256 + threadIdx.x;
    if (e <= NW2) partW[e] = min(lbound(rowptr, N_NODES + 1, e * PART_T), N_NODES);
    if (e >= N_EDGES) {
        if (e < N_EDGES + 32) srcS[e] = 0;   // pad: prefetch reads stay in-bounds
        return;
    }
    int d = dst[e];
    int p = rowptr[d] + atomicAdd(&cursor[d], 1);
    srcS[p] = src[e];
    const float* row = ea + (size_t)e * EDGE_F;
    u32 buf[ROW_U32];
    #pragma unroll
    for (int q = 0; q < ROW_U32; ++q) {
        int k0 = 2 * q, k1 = k0 + 1;
        f16x2 hv = {(f16)((k0 < EDGE_F) ? row[k0] : 0.f),
                    (f16)((k1 < EDGE_F) ? row[k1] : 0.f)};
        buf[q] = __builtin_bit_cast(u32, hv);
    }
    uint4* orow = (uint4*)(eapS + (size_t)p * ROW_U32);
    #pragma unroll
    for (int q4 = 0; q4 < ROW_U32 / 4; ++q4)
        orow[q4] = make_uint4(buf[4 * q4], buf[4 * q4 + 1], buf[4 * q4 + 2], buf[4 * q4 + 3]);
}

// ---------------- embedm: A = x @ W_embed + b via MFMA ----------------------
__global__ __launch_bounds__(256) void k_embedm(const float* __restrict__ x,
                                                const f16* __restrict__ Wef,
                                                const float* __restrict__ b,
                                                float* __restrict__ A) {
    __shared__ f16x8 Wl[12 * 64];   // 12 KB
    for (int i = threadIdx.x; i < 12 * 64; i += 256) Wl[i] = ((const f16x8*)Wef)[i];
    __syncthreads();
    const int lane = threadIdx.x & 63;
    const int col = lane & 15, grp = lane >> 4;
    float bj[4];
    #pragma unroll
    for (int jt = 0; jt < 4; ++jt) bj[jt] = b[jt * 16 + col];
    const int wid = blockIdx.x * 4 + (threadIdx.x >> 6);
    const int nw = gridDim.x * 4;
    for (int c = wid; c < N_NODES / 16; c += nw) {
        const int node = c * 16 + col;
        const float* xr = x + (size_t)node * IN_F;
        f16x8 af[3];
        #pragma unroll
        for (int kt = 0; kt < 3; ++kt) {
            int base = kt * 32 + grp * 8;
            float4 v0 = *(const float4*)(xr + base);
            float4 v1 = (base + 4 < IN_F) ? *(const float4*)(xr + base + 4)
                                          : make_float4(0.f, 0.f, 0.f, 0.f);
            af[kt] = f16x8{(f16)v0.x, (f16)v0.y, (f16)v0.z, (f16)v0.w,
                           (f16)v1.x, (f16)v1.y, (f16)v1.z, (f16)v1.w};
        }
        #pragma unroll
        for (int jt = 0; jt < 4; ++jt) {
            f32x4 c4 = {};
            c4 = __builtin_amdgcn_mfma_f32_16x16x32_f16(af[0], Wl[(0 * 4 + jt) * 64 + lane], c4, 0, 0, 0);
            c4 = __builtin_amdgcn_mfma_f32_16x16x32_f16(af[1], Wl[(1 * 4 + jt) * 64 + lane], c4, 0, 0, 0);
            c4 = __builtin_amdgcn_mfma_f32_16x16x32_f16(af[2], Wl[(2 * 4 + jt) * 64 + lane], c4, 0, 0, 0);
            #pragma unroll
            for (int r = 0; r < 4; ++r)
                A[(size_t)(c * 16 + grp * 4 + r) * HID + jt * 16 + col] = c4[r] + bj[jt];
        }
    }
}

// ---------------- projm: MFMA node projections (layout [n][jt*16+col]) -------
__global__ __launch_bounds__(256, 4) void k_projm(const float* __restrict__ A,
                                                  const float* __restrict__ statsPrev,
                                                  const float* __restrict__ gammaP,
                                                  const float* __restrict__ betaP,
                                                  int applyBN,
                                                  const f16* __restrict__ Wp2L,
                                                  const float* __restrict__ bsig,
                                                  const float* __restrict__ bsp,
                                                  u32* __restrict__ pA,
                                                  u32* __restrict__ pB,
                                                  float* __restrict__ statsOut) {
    __shared__ f16x8 Wl[32 * 64];   // 32 KB
    for (int i = threadIdx.x; i < 32 * 64; i += 256) Wl[i] = ((const f16x8*)Wp2L)[i];
    if (blockIdx.x == 0)
        for (int i = threadIdx.x; i < 128 * 32; i += 256) statsOut[i] = 0.f;
    __syncthreads();
    const int lane = threadIdx.x & 63;
    const int col = lane & 15;
    float sck[2][8], shk[2][8];
    #pragma unroll
    for (int kt = 0; kt < 2; ++kt)
        #pragma unroll
        for (int b = 0; b < 8; ++b) {
            int k = kt * 32 + (lane >> 4) * 8 + b;
            float scv = 1.f, shv = 0.f;
            if (applyBN) {
                float m = statsPrev[k * 32] * (1.f / N_NODES);
                float v = statsPrev[(64 + k) * 32] * (1.f / N_NODES) - m * m;
                scv = rsqrtf(v + BN_EPS) * gammaP[k];
                shv = betaP[k] - m * scv;
            }
            sck[kt][b] = scv;
            shk[kt][b] = shv;
        }
    float bAs[4], bPs[4];
    #pragma unroll
    for (int jt = 0; jt < 4; ++jt) {
        bAs[jt] = bsig[jt * 16 + col] * LOG2E;
        bPs[jt] = bsp[jt * 16 + col] * LOG2E;
    }
    const int wid = blockIdx.x * 4 + (threadIdx.x >> 6);
    const int nw = gridDim.x * 4;
    for (int c = wid; c < N_NODES / 16; c += nw) {
        const int node = c * 16 + col;
        const float4* Arow = (const float4*)(A + (size_t)node * HID);
        f16x8 af[2];
        #pragma unroll
        for (int kt = 0; kt < 2; ++kt) {
            float4 v0 = Arow[kt * 8 + (lane >> 4) * 2];
            float4 v1 = Arow[kt * 8 + (lane >> 4) * 2 + 1];
            float e0 = v0.x * sck[kt][0] + shk[kt][0];
            float e1 = v0.y * sck[kt][1] + shk[kt][1];
            float e2 = v0.z * sck[kt][2] + shk[kt][2];
            float e3 = v0.w * sck[kt][3] + shk[kt][3];
            float e4 = v1.x * sck[kt][4] + shk[kt][4];
            float e5 = v1.y * sck[kt][5] + shk[kt][5];
            float e6 = v1.z * sck[kt][6] + shk[kt][6];
            float e7 = v1.w * sck[kt][7] + shk[kt][7];
            af[kt] = f16x8{(f16)e0, (f16)e1, (f16)e2, (f16)e3,
                           (f16)e4, (f16)e5, (f16)e6, (f16)e7};
        }
        #pragma unroll
        for (int h = 0; h < 2; ++h) {
            f32x4 c4[8];
            #pragma unroll
            for (int jt2 = 0; jt2 < 8; ++jt2) {
                int jt = h * 8 + jt2;
                f32x4 acc = {};
                acc = __builtin_amdgcn_mfma_f32_16x16x32_f16(af[0], Wl[(0 * 16 + jt) * 64 + lane], acc, 0, 0, 0);
                c4[jt2] = __builtin_amdgcn_mfma_f32_16x16x32_f16(af[1], Wl[(1 * 16 + jt) * 64 + lane], acc, 0, 0, 0);
            }
            u32* dstArr = h ? pB : pA;
            #pragma unroll
            for (int jt2 = 0; jt2 < 4; ++jt2)
                #pragma unroll
                for (int r = 0; r < 4; ++r) {
                    float s = fmaf(c4[jt2][r], LOG2E, h ? 0.f : bAs[jt2]);
                    float p = fmaf(c4[jt2 + 4][r], LOG2E, h ? 0.f : bPs[jt2]);
                    int n2 = c * 16 + (lane >> 4) * 4 + r;
                    dstArr[(size_t)n2 * HID + jt2 * 16 + col] = f2bf(s) | (f2bf(p) << 16);
                }
        }
    }
}

// ---------------- nodeagg: R8/R11-verbatim dual-context interleave -----------
// Per-context STEP_COMPUTE (weights read inside) keeps each context's live
// state contained -> no spill. Do NOT share weight reads across contexts
// (R9/R10 regression: forces both contexts' tile state live -> scratch).

#define CTX_DECL_INIT(S, widx)                                                \
    int n##S = __builtin_amdgcn_readfirstlane(partW[widx]);                   \
    const int ne##S = __builtin_amdgcn_readfirstlane(partW[(widx) + 1]);      \
    bool act##S = n##S < ne##S;                                               \
    int rb##S = 0, re##S = 0;                                                 \
    float resid##S = 0.f;                                                     \
    float bsg##S[4], bsp##S[4], accv##S[4];                                   \
    int s0##S = 0, s1##S = 0, s2##S = 0, s3##S = 0;                           \
    {                                                                         \
        _Pragma("unroll")                                                     \
        for (int jt = 0; jt < 4; ++jt) {                                      \
            bsg##S[jt] = 0.f; bsp##S[jt] = 0.f; accv##S[jt] = 0.f;            \
        }                                                                     \
        if (act##S) {                                                         \
            rb##S = __builtin_amdgcn_readfirstlane(rowptr[n##S]);             \
            re##S = __builtin_amdgcn_readfirstlane(rowptr[n##S + 1]);         \
            resid##S = A[(size_t)n##S * HID + lane];                          \
            if (applyBN) resid##S = resid##S * scL + shL;                     \
            _Pragma("unroll")                                                 \
            for (int jt = 0; jt < 4; ++jt) {                                  \
                u32 pb = pBv[(size_t)n##S * HID + jt * 16 + col];             \
                bsg##S[jt] = __uint_as_float(pb << 16);                       \
                bsp##S[jt] = __uint_as_float(pb & 0xffff0000u);               \
            }                                                                 \
            const int* sp = srcS + rb##S + rowb;                              \
            s0##S = sp[0]; s1##S = sp[1]; s2##S = sp[2]; s3##S = sp[3];       \
        }                                                                     \
    }

#define STEP_LOADS(S)                                                         \
    u32 ga##S[4][4];                                                          \
    f16x8 a0##S, a1##S;                                                       \
    if (act##S) {                                                             \
        const u32* g0##S = pAv + (size_t)s0##S * HID + col;                   \
        const u32* g1##S = pAv + (size_t)s1##S * HID + col;                   \
        const u32* g2##S = pAv + (size_t)s2##S * HID + col;                   \
        const u32* g3##S = pAv + (size_t)s3##S * HID + col;                   \
        _Pragma("unroll")                                                     \
        for (int jt = 0; jt < 4; ++jt) {                                      \
            ga##S[jt][0] = g0##S[jt * 16];                                    \
            ga##S[jt][1] = g1##S[jt * 16];                                    \
            ga##S[jt][2] = g2##S[jt * 16];                                    \
            ga##S[jt][3] = g3##S[jt * 16];                                    \
        }                                                                     \
        const f16x8* arow##S = (const f16x8*)(eapS + (size_t)(rb##S + col) * ROW_U32); \
        a0##S = arow##S[grp];                                                 \
        a1##S = arow##S[4 + grp];                                             \
    }

#define STEP_COMPUTE(S)                                                       \
    if (act##S) {                                                             \
        const int cnt##S = re##S - rb##S;                                     \
        if (cnt##S > 0) {                                                     \
            _Pragma("unroll")                                                 \
            for (int jt = 0; jt < 4; ++jt) {                                  \
                f32x4 cs = {bsg##S[jt], bsg##S[jt], bsg##S[jt], bsg##S[jt]};  \
                f32x4 cp = {bsp##S[jt], bsp##S[jt], bsp##S[jt], bsp##S[jt]};  \
                f16x8 w0s = Wlds[(jt) * 64 + lane];                           \
                f16x8 w1s = Wlds[(8 + jt) * 64 + lane];                       \
                f16x8 w0p = Wlds[(4 + jt) * 64 + lane];                       \
                f16x8 w1p = Wlds[(12 + jt) * 64 + lane];                      \
                cs = __builtin_amdgcn_mfma_f32_16x16x32_f16(a0##S, w0s, cs, 0, 0, 0); \
                cs = __builtin_amdgcn_mfma_f32_16x16x32_f16(a1##S, w1s, cs, 0, 0, 0); \
                cp = __builtin_amdgcn_mfma_f32_16x16x32_f16(a0##S, w0p, cp, 0, 0, 0); \
                cp = __builtin_amdgcn_mfma_f32_16x16x32_f16(a1##S, w1p, cp, 0, 0, 0); \
                _Pragma("unroll")                                             \
                for (int r = 0; r < 4; ++r) {                                 \
                    float s_ = cs[r] + __uint_as_float(ga##S[jt][r] << 16);   \
                    float p_ = cp[r] + __uint_as_float(ga##S[jt][r] & 0xffff0000u); \
                    float g_ = __builtin_amdgcn_rcpf(1.f + exp2f(-s_));       \
                    float m_ = fmaxf(p_, 0.f) + log2f(1.f + exp2f(-fabsf(p_))); \
                    accv##S[jt] += (rowb + r < cnt##S) ? g_ * m_ : 0.f;       \
                }                                                             \
            }                                                                 \
            rb##S += 16;                                                      \
        }                                                                     \
        while (rb##S >= re##S) {                                              \
            _Pragma("unroll")                                                 \
            for (int jt = 0; jt < 4; ++jt) {                                  \
                accv##S[jt] += __shfl_xor(accv##S[jt], 16);                   \
                accv##S[jt] += __shfl_xor(accv##S[jt], 32);                   \
            }                                                                 \
            float accSel = (lane & 32) ? ((lane & 16) ? accv##S[3] : accv##S[2]) \
                                       : ((lane & 16) ? accv##S[1] : accv##S[0]); \
            float outv = resid##S + accSel * LN2;                             \
            Aout[(size_t)n##S * HID + lane] = outv;                           \
            lsum += outv;                                                     \
            lsq += outv * outv;                                               \
            accv##S[0] = accv##S[1] = accv##S[2] = accv##S[3] = 0.f;          \
            rb##S = re##S;                                                    \
            ++n##S;                                                           \
            if (n##S >= ne##S) { act##S = false; break; }                     \
            re##S = __builtin_amdgcn_readfirstlane(rowptr[n##S + 1]);         \
            resid##S = A[(size_t)n##S * HID + lane];                          \
            if (applyBN) resid##S = resid##S * scL + shL;                     \
            _Pragma("unroll")                                                 \
            for (int jt = 0; jt < 4; ++jt) {                                  \
                u32 pb = pBv[(size_t)n##S * HID + jt * 16 + col];             \
                bsg##S[jt] = __uint_as_float(pb << 16);                       \
                bsp##S[jt] = __uint_as_float(pb & 0xffff0000u);               \
            }                                                                 \
        }                                                                     \
        if (act##S) {                                                         \
            const int* sp##S = srcS + rb##S + rowb;                           \
            s0##S = sp##S[0]; s1##S = sp##S[1];                               \
            s2##S = sp##S[2]; s3##S = sp##S[3];                               \
        }                                                                     \
    }

__global__ __launch_bounds__(256, 4) void k_nodeagg(const float* __restrict__ A,
                                                    const float* __restrict__ statsPrev,
                                                    const float* __restrict__ gammaP,
                                                    const float* __restrict__ betaP,
                                                    int applyBN,
                                                    const u32* __restrict__ pAv,
                                                    const u32* __restrict__ pBv,
                                                    const u32* __restrict__ eapS,
                                                    const int* __restrict__ srcS,
                                                    const int* __restrict__ rowptr,
                                                    const int* __restrict__ partW,
                                                    const f16* __restrict__ Wf16L,
                                                    float* __restrict__ Aout,
                                                    float* __restrict__ statsOut) {
    __shared__ f16x8 Wlds[16 * 64];   // 16 KB B-fragments
    __shared__ float redS[256], redQ[256];
    for (int i = threadIdx.x; i < 16 * 64; i += 256)
        Wlds[i] = ((const f16x8*)Wf16L)[i];

    const int lane = threadIdx.x & 63;
    const int col = lane & 15;
    const int grp = lane >> 4;
    const int rowb = grp * 4;

    float scL = 1.f, shL = 0.f;
    if (applyBN) {
        float m = statsPrev[lane * 32] * (1.f / N_NODES);
        float v = statsPrev[(64 + lane) * 32] * (1.f / N_NODES) - m * m;
        scL = rsqrtf(v + BN_EPS) * gammaP[lane];
        shL = betaP[lane] - m * scL;
    }
    __syncthreads();

    const int w2 = (((blockIdx.x << 2) + (threadIdx.x >> 6)) << 1);
    float lsum = 0.f, lsq = 0.f;

    CTX_DECL_INIT(A, w2)
    CTX_DECL_INIT(B, w2 + 1)

    while (actA || actB) {
        STEP_LOADS(A)
        STEP_LOADS(B)
        STEP_COMPUTE(A)
        STEP_COMPUTE(B)
    }

    redS[threadIdx.x] = lsum;
    redQ[threadIdx.x] = lsq;
    __syncthreads();
    if (threadIdx.x < 64) {
        float s = redS[threadIdx.x] + redS[threadIdx.x + 64] + redS[threadIdx.x + 128] + redS[threadIdx.x + 192];
        float q = redQ[threadIdx.x] + redQ[threadIdx.x + 64] + redQ[threadIdx.x + 128] + redQ[threadIdx.x + 192];
        unsafeAtomicAdd(&statsOut[threadIdx.x * 32], s);
        unsafeAtomicAdd(&statsOut[(64 + threadIdx.x) * 32], q);
    }
}

// ---------------- poolout: per-graph sum + final BN + 2-layer readout --------
__global__ __launch_bounds__(256) void k_poolout(const float* __restrict__ A,
                                                 const float* __restrict__ stats,
                                                 const float* __restrict__ gamma,
                                                 const float* __restrict__ beta,
                                                 const int* __restrict__ gstart,
                                                 const float* __restrict__ Wfc,
                                                 const float* __restrict__ bfc,
                                                 const float* __restrict__ Wout,
                                                 const float* __restrict__ bout,
                                                 float* __restrict__ out) {
    const int g = blockIdx.x;
    const int lane = threadIdx.x & 63;
    const int wv = threadIdx.x >> 6;
    const int rb = gstart[g], re = gstart[g + 1];
    float s = 0.f;
    for (int r = rb + wv; r < re; r += 4) s += A[(size_t)r * HID + lane];
    __shared__ float red[4][64];
    __shared__ float gfeat[64];
    red[wv][lane] = s;
    __syncthreads();
    if (threadIdx.x < 64) {
        float t = red[0][lane] + red[1][lane] + red[2][lane] + red[3][lane];
        float m = stats[lane * 32] * (1.f / N_NODES);
        float v = stats[(64 + lane) * 32] * (1.f / N_NODES) - m * m;
        float scv = rsqrtf(v + BN_EPS) * gamma[lane];
        float shv = beta[lane] - m * scv;
        gfeat[lane] = scv * t + shv * (float)(re - rb);
    }
    __syncthreads();
    __shared__ float r2[128];
    if (threadIdx.x < 128) {
        float p = bfc[threadIdx.x];
        #pragma unroll 8
        for (int k = 0; k < 64; ++k) p += gfeat[k] * Wfc[k * PRED + threadIdx.x];
        r2[threadIdx.x] = p * Wout[threadIdx.x];
    }
    __syncthreads();
    if (threadIdx.x < 64) {
        float v2 = r2[threadIdx.x] + r2[threadIdx.x + 64];
        #pragma unroll
        for (int off = 32; off > 0; off >>= 1) v2 += __shfl_down(v2, off);
        if (threadIdx.x == 0) out[g] = v2 + bout[0];
    }
}

extern "C" void kernel_launch(void* const* d_in, const int* in_sizes, int n_in,
                              void* d_out, int out_size, void* d_ws, size_t ws_size,
                              hipStream_t stream) {
    const float* x         = (const float*)d_in[0];
    const float* edge_attr = (const float*)d_in[1];
    const int*   src       = (const int*)d_in[2];
    const int*   dst       = (const int*)d_in[3];
    const int*   gidx      = (const int*)d_in[4];
    const float* W_embed   = (const float*)d_in[6];
    const float* b_embed   = (const float*)d_in[7];
    const float* W_sig     = (const float*)d_in[8];
    const float* b_sig     = (const float*)d_in[9];
    const float* W_sp      = (const float*)d_in[10];
    const float* b_sp      = (const float*)d_in[11];
    const float* bn_gamma  = (const float*)d_in[12];
    const float* bn_beta   = (const float*)d_in[13];
    const float* W_fc      = (const float*)d_in[14];
    const float* b_fc      = (const float*)d_in[15];
    const float* W_out     = (const float*)d_in[16];
    const float* b_out     = (const float*)d_in[17];
    float* out = (float*)d_out;

    const size_t NH = (size_t)N_NODES * HID;
    float* ws     = (float*)d_ws;
    float* A      = ws;                                   // NH f32
    u32*   pA     = (u32*)(A + NH);                       // NH u32, layout [n][jt*16+col]
    u32*   pB     = pA + NH;                              // NH u32
    u32*   eapS   = pB + NH;                              // (E+32)*24 u32
    int*   srcS   = (int*)(eapS + (size_t)(N_EDGES + 32) * ROW_U32);  // E+32
    int*   rowptr = srcS + N_EDGES + 32;                  // N+1
    int*   deg    = rowptr + N_NODES + 1;                 // N (+ cursor N, zeroed together)
    int*   cursor = deg + N_NODES;                        // N
    int*   partial    = cursor + N_NODES;                 // 256
    int*   partW  = partial + 256;                        // NW2+1
    int*   gstart = partW + NW2 + 2;                      // 501
    f16*   Wf16   = (f16*)(((size_t)(gstart + 504) + 15) & ~(size_t)15);  // 16B-aligned
    f16*   Wp2    = Wf16 + 3 * 2 * 8 * 64 * 8;
    f16*   Wef    = Wp2 + 3 * 2 * 16 * 64 * 8;
    float* stats  = (float*)(Wef + 3 * 4 * 64 * 8);       // 3 * 4096 f32

    // ---- prep (weights, zeros, gstart, rowptr[N]), CSR, rank+pack ----
    k_prep<<<(10485 + 2 * N_NODES + 255) / 256, 256, 0, stream>>>(
        W_sig, W_sp, W_embed, gidx, Wf16, Wp2, Wef, gstart, rowptr, deg);
    k_hist<<<(N_EDGES + 255) / 256, 256, 0, stream>>>(dst, deg);
    k_scanA<<<SCAN_BLOCKS, 256, 0, stream>>>(deg, partial);
    k_scanC<<<SCAN_BLOCKS, 256, 0, stream>>>(deg, partial, rowptr);
    k_rank<<<(N_EDGES + 32 + 255) / 256, 256, 0, stream>>>(dst, src, edge_attr, rowptr,
                                                           cursor, srcS, eapS, partW);
    k_embedm<<<512, 256, 0, stream>>>(x, Wef, b_embed, A);

    for (int i = 0; i < 3; ++i) {
        const float* stPrev = stats + (size_t)(i > 0 ? i - 1 : 0) * 4096;
        const float* gP     = bn_gamma + (i > 0 ? i - 1 : 0) * HID;
        const float* bP     = bn_beta + (i > 0 ? i - 1 : 0) * HID;
        float* stOut        = stats + (size_t)i * 4096;
        int applyBN = (i > 0) ? 1 : 0;
        k_projm<<<512, 256, 0, stream>>>(A, stPrev, gP, bP, applyBN,
                                         Wp2 + (size_t)i * 2 * 16 * 64 * 8,
                                         b_sig + i * HID, b_sp + i * HID,
                                         pA, pB, stOut);
        k_nodeagg<<<NAGG_BLOCKS, 256, 0, stream>>>(A, stPrev, gP, bP, applyBN,
                                                   pA, pB, eapS, srcS, rowptr, partW,
                                                   Wf16 + (size_t)i * 2 * 8 * 64 * 8,
                                                   A, stOut);
    }

    k_poolout<<<N_GRAPHS, 256, 0, stream>>>(A, stats + 2 * 4096, bn_gamma + 2 * HID,
                                            bn_beta + 2 * HID, gstart,
                                            W_fc, b_fc, W_out, b_out, out);
}